// Round 1
// baseline (976.548 us; speedup 1.0000x reference)
//
#include <hip/hip_runtime.h>
#include <hip/hip_bf16.h>

#define TT 512
#define MCELLS 16384            // B*N = 256*64
#define LOG2E 1.44269504088896340736f

typedef __attribute__((ext_vector_type(8))) short bf16x8;
typedef __attribute__((ext_vector_type(4))) float f32x4;
typedef __attribute__((ext_vector_type(4))) short s16x4;

__device__ __forceinline__ short f2bf(float f) {
    __hip_bfloat16 h = __float2bfloat16(f);
    return __builtin_bit_cast(short, h);
}

// Persistent LSTM kernel.
// grid = 256 blocks, block = 256 threads (4 waves). Each wave owns 16 cells
// (cell = blockIdx*64 + wave*16 + (lane&15)) for all T steps.
// Swapped MFMA: D[g4, cell] = sum_h W_hh[g4,h] * h[cell,h] using
// v_mfma_f32_16x16x32_bf16 (A = W tile from LDS in frag order, B = h^T).
__global__ __launch_bounds__(256, 1)
void lstm_net_kernel(const float* __restrict__ input,
                     const float* __restrict__ w1,
                     const float* __restrict__ b1,
                     const float* __restrict__ w2,
                     const float* __restrict__ b2,
                     const float* __restrict__ W_ih,
                     const float* __restrict__ W_hh,
                     const float* __restrict__ b_ih,
                     const float* __restrict__ b_hh,
                     const float* __restrict__ wg,
                     const float* __restrict__ bg,
                     float* __restrict__ out)
{
    // W_hh in MFMA A-fragment order: frag f = jm*2+kk (jm tile of 16 g4-rows,
    // kk half of K=64), 64 lanes x 16B each -> conflict-free ds_read_b128.
    __shared__ bf16x8 AW[32 * 64];          // 32 KB
    __shared__ float  ldsWih[256];
    __shared__ float  ldsBs[256];
    // per-wave h buffer: 16 rows (cells) x 144 B (64 bf16 + pad, 16B-mult stride)
    __shared__ __align__(16) char hbuf[4 * 16 * 144];

    const int tid  = threadIdx.x;
    const int wv   = tid >> 6;
    const int lane = tid & 63;
    const int lo   = lane & 15;
    const int hi   = lane >> 4;

    // ---- one-time staging ----
    for (int f = wv; f < 32; f += 4) {
        const int jm = f >> 1, kk = f & 1;
        const int row = jm * 16 + lo;          // g4 row
        const int kb  = kk * 32 + hi * 8;      // k (hdim) base for this lane
        const float* src = W_hh + row * 64 + kb;
        bf16x8 v;
        #pragma unroll
        for (int e = 0; e < 8; ++e) v[e] = f2bf(src[e]);
        AW[f * 64 + lane] = v;
    }
    if (tid < 256) {
        ldsWih[tid] = W_ih[tid];
        ldsBs[tid]  = b_ih[tid] + b_hh[tid];
    }
    char* hwave = hbuf + wv * (16 * 144);
    for (int o = lane; o < 576; o += 64) ((unsigned int*)hwave)[o] = 0u;  // h0 = 0

    // ---- per-lane constants ----
    const int cell = blockIdx.x * 64 + wv * 16 + lo;
    const int n    = cell & 63;
    float a_n = 0.f, c_n = 0.f;
    #pragma unroll
    for (int h = 0; h < 10; ++h) {
        a_n += w1[n * 10 + h] * w2[n * 10 + h];   // per-neuron affine collapse
        c_n += b1[n * 10 + h] * w2[n * 10 + h];
    }
    c_n += b2[n];
    f32x4 wgj[4];
    #pragma unroll
    for (int j = 0; j < 4; ++j)
        wgj[j] = *(const f32x4*)(wg + 16 * j + 4 * hi);
    const float bgv = bg[0];

    __syncthreads();

    f32x4 cst[4] = { {0,0,0,0},{0,0,0,0},{0,0,0,0},{0,0,0,0} };  // c state
    float gm2 = 0.f, gm1 = 0.f;                                   // g_{t-2}, g_{t-1}
    const float* inP  = input + cell;
    float*       outP = out + cell;
    float raw_next = inP[0];

    for (int t = 0; t < TT; ++t) {
        const float raw = raw_next;
        raw_next = inP[((t + 1 < TT) ? (t + 1) : t) * MCELLS];    // prefetch
        const float x = raw * a_n + c_n;                          // outLin[t,cell]

        // softplus(x-1) = ln2 * log2(1 + 2^(log2e*(x-1)))
        const float spE = __builtin_amdgcn_exp2f(LOG2E * (x - 1.f));
        const float sp  = 0.69314718056f * __builtin_amdgcn_logf(1.f + spE);
        if (t >= 1 && lane < 16)
            outP[t * MCELLS] = (t == 1) ? sp : gm2 * sp;          // g_prev[t]=g_{t-2}

        // acc init: x*W_ih[g4] + (b_ih+b_hh)[g4], broadcast LDS reads
        f32x4 acc[16];
        #pragma unroll
        for (int jm = 0; jm < 16; ++jm) {
            const f32x4 wi = *(const f32x4*)&ldsWih[jm * 16 + hi * 4];
            const f32x4 bs = *(const f32x4*)&ldsBs[jm * 16 + hi * 4];
            #pragma unroll
            for (int r = 0; r < 4; ++r) acc[jm][r] = x * wi[r] + bs[r];
        }

        // B-frags: h^T, lane -> cell=lo, hdims kk*32 + hi*8 .. +8
        const bf16x8 bf0 = *(const bf16x8*)(hwave + lo * 144 + hi * 16);
        const bf16x8 bf1 = *(const bf16x8*)(hwave + lo * 144 + 64 + hi * 16);

        #pragma unroll
        for (int jm = 0; jm < 16; ++jm) {
            acc[jm] = __builtin_amdgcn_mfma_f32_16x16x32_bf16(
                AW[(jm * 2 + 0) * 64 + lane], bf0, acc[jm], 0, 0, 0);
            acc[jm] = __builtin_amdgcn_mfma_f32_16x16x32_bf16(
                AW[(jm * 2 + 1) * 64 + lane], bf1, acc[jm], 0, 0, 0);
        }

        // activations: lane handles (cell=lo, hdim = 16j + 4hi + r)
        float gacc = 0.f;
        #pragma unroll
        for (int j = 0; j < 4; ++j) {
            short hp0, hp1, hp2, hp3;
            #pragma unroll
            for (int r = 0; r < 4; ++r) {
                const float ip = acc[j][r];        // i: g4 = hdim
                const float fp = acc[j + 4][r];    // f: hdim + 64
                const float gp = acc[j + 8][r];    // g: hdim + 128
                const float op = acc[j + 12][r];   // o: hdim + 192

                const float Ei  = __builtin_amdgcn_exp2f(-LOG2E * ip);
                const float gpc = fminf(fmaxf(gp, -15.f), 15.f);
                const float Eg  = __builtin_amdgcn_exp2f(2.f * LOG2E * gpc);
                // i*g = (Eg-1) / ((Eg+1)(1+Ei))  -- one shared rcp
                const float ig  = (Eg - 1.f) *
                    __builtin_amdgcn_rcpf((Eg + 1.f) * (1.f + Ei));
                const float Ef  = __builtin_amdgcn_exp2f(-LOG2E * fp);
                const float fg  = __builtin_amdgcn_rcpf(1.f + Ef);
                const float cp  = fg * cst[j][r] + ig;
                cst[j][r] = cp;
                const float cpc = fminf(fmaxf(cp, -15.f), 15.f);
                const float Ec  = __builtin_amdgcn_exp2f(2.f * LOG2E * cpc);
                const float Eo  = __builtin_amdgcn_exp2f(-LOG2E * op);
                // h = o*tanh(c) = (Ec-1) / ((Ec+1)(1+Eo))
                const float hv  = (Ec - 1.f) *
                    __builtin_amdgcn_rcpf((Ec + 1.f) * (1.f + Eo));
                gacc += hv * wgj[j][r];
                if (r == 0) hp0 = f2bf(hv);
                if (r == 1) hp1 = f2bf(hv);
                if (r == 2) hp2 = f2bf(hv);
                if (r == 3) hp3 = f2bf(hv);
            }
            s16x4 pk; pk[0] = hp0; pk[1] = hp1; pk[2] = hp2; pk[3] = hp3;
            // row lo, hdims 16j+4hi .. +4  (bf16, contiguous)
            *(s16x4*)(hwave + lo * 144 + 32 * j + 8 * hi) = pk;
        }

        // g_t[cell] = sum_h h*wg + bg : reduce over hi-groups (lanes ^16, ^32)
        gacc += __shfl_xor(gacc, 16);
        gacc += __shfl_xor(gacc, 32);
        const float g_t = gacc + bgv;
        if (t == 0 && lane < 16) outP[0] = g_t * sp;   // g_prev[0] = g_0
        gm2 = gm1; gm1 = g_t;
    }
}

extern "C" void kernel_launch(void* const* d_in, const int* in_sizes, int n_in,
                              void* d_out, int out_size, void* d_ws, size_t ws_size,
                              hipStream_t stream) {
    const float* input = (const float*)d_in[0];
    const float* w1    = (const float*)d_in[1];
    const float* b1    = (const float*)d_in[2];
    const float* w2    = (const float*)d_in[3];
    const float* b2    = (const float*)d_in[4];
    const float* W_ih  = (const float*)d_in[5];
    const float* W_hh  = (const float*)d_in[6];
    const float* b_ih  = (const float*)d_in[7];
    const float* b_hh  = (const float*)d_in[8];
    const float* wg    = (const float*)d_in[9];
    const float* bg    = (const float*)d_in[10];

    lstm_net_kernel<<<dim3(256), dim3(256), 0, stream>>>(
        input, w1, b1, w2, b2, W_ih, W_hh, b_ih, b_hh, wg, bg, (float*)d_out);
}

// Round 2
// 812.524 us; speedup vs baseline: 1.2019x; 1.2019x over previous
//
#include <hip/hip_runtime.h>
#include <hip/hip_bf16.h>

#define TT 512
#define MCELLS 16384            // B*N = 256*64
#define LOG2E 1.44269504088896340736f
#define LN2   0.69314718055994530942f

typedef __attribute__((ext_vector_type(8))) short bf16x8;
typedef __attribute__((ext_vector_type(4))) float f32x4;

__device__ __forceinline__ short f2bf(float f) {
    __hip_bfloat16 h = __float2bfloat16(f);
    return __builtin_bit_cast(short, h);
}
// two f32 -> packed bf16 dword (low16 = a, high16 = b), RNE in HW
__device__ __forceinline__ unsigned cvtpk(float a, float b) {
    unsigned r;
    asm("v_cvt_pk_bf16_f32 %0, %1, %2" : "=v"(r) : "v"(a), "v"(b));
    return r;
}

// Persistent LSTM. grid = 1024 blocks x 128 threads (2 waves).
// Each block owns 16 cells (cell = blockIdx*16 + (lane&15)); the two waves
// split the hidden dim: wave w handles hdims [w*32, w*32+32) for all 4 gates
// (jm tiles gate*4 + w*2 + j). Swapped MFMA D[gate-rows, cell] with
// A = W_hh rows in VGPR-resident frag order, B = h^T from LDS.
// K extended to 96: 3rd MFMA carries x*W_ih + bias (B-ext rows = [x, 1]).
__global__ __launch_bounds__(128, 2)
void lstm_net_kernel(const float* __restrict__ input,
                     const float* __restrict__ w1,
                     const float* __restrict__ b1,
                     const float* __restrict__ w2,
                     const float* __restrict__ b2,
                     const float* __restrict__ W_ih,
                     const float* __restrict__ W_hh,
                     const float* __restrict__ b_ih,
                     const float* __restrict__ b_hh,
                     const float* __restrict__ wg,
                     const float* __restrict__ bg,
                     float* __restrict__ out)
{
    // h double buffer: 2 x 16 rows(cells) x 144B (64 bf16 + pad; 16B-aligned rows)
    __shared__ __align__(16) char hbuf[2 * 16 * 144];
    __shared__ float gpart[4][2][16];   // 4-slot ring: g written @t, read @t+2

    const int tid  = threadIdx.x;
    const int wv   = tid >> 6;          // 0/1: hdim half
    const int lane = tid & 63;
    const int lo   = lane & 15;
    const int hi   = lane >> 4;

    for (int o = tid; o < (2 * 16 * 144) / 4; o += 128)
        ((unsigned*)hbuf)[o] = 0u;      // h0 = 0 (both buffers)

    // ---- per-cell constants ----
    const int cell = blockIdx.x * 16 + lo;
    const int n    = cell & 63;
    float a_n = 0.f, c_n = 0.f;
    #pragma unroll
    for (int k = 0; k < 10; ++k) {
        a_n += w1[n * 10 + k] * w2[n * 10 + k];   // per-neuron affine collapse
        c_n += b1[n * 10 + k] * w2[n * 10 + k];
    }
    c_n += b2[n];
    f32x4 wgv[2];
    #pragma unroll
    for (int j = 0; j < 2; ++j)
        wgv[j] = *(const f32x4*)(wg + wv * 32 + j * 16 + hi * 4);
    const float bgv = bg[0];

    // ---- A-fragments resident in VGPRs ----
    // jj = gate*2 + j ; jm = gate*4 + wv*2 + j ; rows = jm*16 + lo
    bf16x8 AWf[8][3];
    #pragma unroll
    for (int jj = 0; jj < 8; ++jj) {
        const int gate = jj >> 1, j = jj & 1;
        const int row = (gate * 4 + wv * 2 + j) * 16 + lo;
        #pragma unroll
        for (int kk = 0; kk < 2; ++kk) {
            const float* src = W_hh + row * 64 + kk * 32 + hi * 8;
            bf16x8 v;
            #pragma unroll
            for (int e = 0; e < 8; ++e) v[e] = f2bf(src[e]);
            AWf[jj][kk] = v;
        }
        bf16x8 vx = {};                 // K-ext: col64 = W_ih, col65 = bias
        if (hi == 0) {
            vx[0] = f2bf(W_ih[row]);
            vx[1] = f2bf(b_ih[row] + b_hh[row]);
        }
        AWf[jj][2] = vx;
    }

    f32x4 zero4 = {0.f, 0.f, 0.f, 0.f};
    f32x4 cst[2] = {zero4, zero4};
    float sp0 = 0.f;
    const float* inP  = input + cell;
    float*       outP = out + cell;
    float raw_next = inP[0];

    __syncthreads();

    for (int t = 0; t < TT; ++t) {
        const float raw = raw_next;
        raw_next = inP[((t + 1 < TT) ? (t + 1) : t) * MCELLS];
        const float x = raw * a_n + c_n;            // outLin[t,cell]

        // B-ext frag: rows 64..95 of B = [x, 1, 0...] (per cell = lo)
        bf16x8 bx = {};
        {
            const short xb = f2bf(x);
            bx[0] = (hi == 0) ? xb : (short)0;
            bx[1] = (hi == 0) ? (short)0x3F80 : (short)0;   // bf16(1.0)
        }

        // h B-frags: cell = lo, hdims hi*8.. (+32 for second half)
        const char* hrd = hbuf + (t & 1) * 2304 + lo * 144;
        const bf16x8 bf0 = *(const bf16x8*)(hrd + hi * 16);
        const bf16x8 bf1 = *(const bf16x8*)(hrd + 64 + hi * 16);

        f32x4 acc[8];
        #pragma unroll
        for (int jj = 0; jj < 8; ++jj) {
            acc[jj] = __builtin_amdgcn_mfma_f32_16x16x32_bf16(AWf[jj][2], bx,  zero4, 0, 0, 0);
            acc[jj] = __builtin_amdgcn_mfma_f32_16x16x32_bf16(AWf[jj][0], bf0, acc[jj], 0, 0, 0);
            acc[jj] = __builtin_amdgcn_mfma_f32_16x16x32_bf16(AWf[jj][1], bf1, acc[jj], 0, 0, 0);
        }

        // softplus(x-1), only wave 0 needs it
        float sp = 0.f;
        if (wv == 0) {
            const float spE = __builtin_amdgcn_exp2f(LOG2E * (x - 1.f));
            sp = LN2 * __builtin_amdgcn_logf(1.f + spE);
        }

        // activations: lane handles (cell=lo, hdim = wv*32 + j*16 + hi*4 + r)
        float gacc = 0.f;
        char* hwr = hbuf + ((t + 1) & 1) * 2304 + lo * 144 + wv * 64;
        #pragma unroll
        for (int j = 0; j < 2; ++j) {
            float hv[4];
            #pragma unroll
            for (int r = 0; r < 4; ++r) {
                const float ip = acc[j][r];
                const float fp = acc[2 + j][r];
                const float gp = acc[4 + j][r];
                const float op = acc[6 + j][r];

                const float Ei  = __builtin_amdgcn_exp2f(-LOG2E * ip);
                const float Ef  = __builtin_amdgcn_exp2f(-LOG2E * fp);
                const float gpc = __builtin_amdgcn_fmed3f(gp, -15.f, 15.f);
                const float Eg  = __builtin_amdgcn_exp2f(2.f * LOG2E * gpc);
                // c' = sig(f)*c + sig(i)*tanh(g), single rcp:
                const float D1  = 1.f + Ef;
                const float D2  = (Eg + 1.f) * (1.f + Ei);
                const float num = cst[j][r] * D2 + (Eg - 1.f) * D1;
                const float cp  = num * __builtin_amdgcn_rcpf(D1 * D2);
                cst[j][r] = cp;
                const float cpc = __builtin_amdgcn_fmed3f(cp, -15.f, 15.f);
                const float Ec  = __builtin_amdgcn_exp2f(2.f * LOG2E * cpc);
                const float Eo  = __builtin_amdgcn_exp2f(-LOG2E * op);
                // h = sig(o)*tanh(c), single rcp:
                const float h   = (Ec - 1.f) *
                    __builtin_amdgcn_rcpf((Ec + 1.f) * (1.f + Eo));
                hv[r] = h;
                gacc += h * wgv[j][r];
            }
            uint2 pk;
            pk.x = cvtpk(hv[0], hv[1]);
            pk.y = cvtpk(hv[2], hv[3]);
            *(uint2*)(hwr + j * 32 + hi * 8) = pk;   // hdims wv*32+j*16+hi*4..+4
        }

        // per-wave partial of g_t = sum_h h*wg (over this wave's 32 hdims)
        gacc += __shfl_xor(gacc, 16);
        gacc += __shfl_xor(gacc, 32);
        if (hi == 0) gpart[t & 3][wv][lo] = gacc;

        // output: out[t] = g_prev[t] * sp[t]; g_prev = {g_0, 1, g_{t-2}...}
        if (wv == 0) {
            if (t == 0) {
                sp0 = sp;
            } else if (t == 1) {
                if (hi == 0) outP[MCELLS] = sp;
            } else {
                const float g = gpart[(t - 2) & 3][0][lo] +
                                gpart[(t - 2) & 3][1][lo] + bgv;
                if (hi == 0) {
                    outP[t * MCELLS] = g * sp;
                    if (t == 2) outP[0] = g * sp0;   // g_prev[0] = g_0
                }
            }
        }
        __syncthreads();   // h(t+1) visible; gpart ring ordered
    }
}

extern "C" void kernel_launch(void* const* d_in, const int* in_sizes, int n_in,
                              void* d_out, int out_size, void* d_ws, size_t ws_size,
                              hipStream_t stream) {
    const float* input = (const float*)d_in[0];
    const float* w1    = (const float*)d_in[1];
    const float* b1    = (const float*)d_in[2];
    const float* w2    = (const float*)d_in[3];
    const float* b2    = (const float*)d_in[4];
    const float* W_ih  = (const float*)d_in[5];
    const float* W_hh  = (const float*)d_in[6];
    const float* b_ih  = (const float*)d_in[7];
    const float* b_hh  = (const float*)d_in[8];
    const float* wg    = (const float*)d_in[9];
    const float* bg    = (const float*)d_in[10];

    lstm_net_kernel<<<dim3(1024), dim3(128), 0, stream>>>(
        input, w1, b1, w2, b2, W_ih, W_hh, b_ih, b_hh, wg, bg, (float*)d_out);
}

// Round 3
// 762.006 us; speedup vs baseline: 1.2815x; 1.0663x over previous
//
#include <hip/hip_runtime.h>
#include <hip/hip_bf16.h>

#define TT 512
#define MCELLS 16384            // B*N = 256*64
#define LOG2E 1.44269504088896340736f
#define LN2   0.69314718055994530942f

typedef __attribute__((ext_vector_type(8))) short bf16x8;
typedef __attribute__((ext_vector_type(4))) float f32x4;

__device__ __forceinline__ short f2bf(float f) {
    __hip_bfloat16 h = __float2bfloat16(f);
    return __builtin_bit_cast(short, h);
}
// two f32 -> packed bf16 dword (low16 = a, high16 = b), RNE in HW
__device__ __forceinline__ unsigned cvtpk(float a, float b) {
    unsigned r;
    asm("v_cvt_pk_bf16_f32 %0, %1, %2" : "=v"(r) : "v"(a), "v"(b));
    return r;
}

// Persistent LSTM. grid = 1024 blocks x 256 threads (4 waves).
// Each block owns 16 cells (cell = blockIdx*16 + (lane&15)); the four waves
// split the hidden dim: wave w handles hdims [w*16, w*16+16) for all 4 gates
// (jm tile = gate*4 + w). Swapped MFMA D[gate-rows, cell] with A = W_hh rows
// VGPR-resident in frag order, B = h^T from LDS (double-buffered).
// K extended to 96: 3rd MFMA carries x*W_ih + bias (B-ext rows = [x, 1]).
// 4 waves/SIMD (from 4 different blocks) overlap trans-pipe and VALU phases.
__global__ __launch_bounds__(256, 4)
void lstm_net_kernel(const float* __restrict__ input,
                     const float* __restrict__ w1,
                     const float* __restrict__ b1,
                     const float* __restrict__ w2,
                     const float* __restrict__ b2,
                     const float* __restrict__ W_ih,
                     const float* __restrict__ W_hh,
                     const float* __restrict__ b_ih,
                     const float* __restrict__ b_hh,
                     const float* __restrict__ wg,
                     const float* __restrict__ bg,
                     float* __restrict__ out)
{
    // h double buffer: 2 x 16 rows(cells) x 144B (64 bf16 + pad; stride 36 dw
    // -> max 2-way bank aliasing on b128 reads, which is free)
    __shared__ __align__(16) char hbuf[2 * 16 * 144];
    __shared__ float gpart[4][4][16];   // ring: slot t&3 written @t, read @t+2

    const int tid  = threadIdx.x;
    const int wv   = tid >> 6;          // 0..3: 16-hdim slice
    const int lane = tid & 63;
    const int lo   = lane & 15;
    const int hi   = lane >> 4;

    for (int o = tid; o < (2 * 16 * 144) / 4; o += 256)
        ((unsigned*)hbuf)[o] = 0u;      // h0 = 0 (both buffers)

    // ---- per-cell constants ----
    const int cell = blockIdx.x * 16 + lo;
    const int n    = cell & 63;
    float a_n = 0.f, c_n = 0.f;
    #pragma unroll
    for (int k = 0; k < 10; ++k) {
        a_n += w1[n * 10 + k] * w2[n * 10 + k];   // per-neuron affine collapse
        c_n += b1[n * 10 + k] * w2[n * 10 + k];
    }
    c_n += b2[n];
    const f32x4 wgv = *(const f32x4*)(wg + wv * 16 + hi * 4);
    const float bgv = bg[0];

    // ---- A-fragments resident in VGPRs ----
    // gate g: jm = g*4 + wv ; rows = jm*16 + lo
    bf16x8 AWf[4][3];
    #pragma unroll
    for (int g = 0; g < 4; ++g) {
        const int row = (g * 4 + wv) * 16 + lo;
        #pragma unroll
        for (int kk = 0; kk < 2; ++kk) {
            const float* src = W_hh + row * 64 + kk * 32 + hi * 8;
            bf16x8 v;
            #pragma unroll
            for (int e = 0; e < 8; ++e) v[e] = f2bf(src[e]);
            AWf[g][kk] = v;
        }
        bf16x8 vx = {};                 // K-ext: col64 = W_ih, col65 = bias
        if (hi == 0) {
            vx[0] = f2bf(W_ih[row]);
            vx[1] = f2bf(b_ih[row] + b_hh[row]);
        }
        AWf[g][2] = vx;
    }

    const f32x4 zero4 = {0.f, 0.f, 0.f, 0.f};
    f32x4 cst = zero4;
    float sp0 = 0.f;
    const float* inP  = input + cell;
    float*       outP = out + cell;
    float raw_next = inP[0];

    __syncthreads();

    for (int t = 0; t < TT; ++t) {
        const float raw = raw_next;
        raw_next = inP[((t + 1 < TT) ? (t + 1) : t) * MCELLS];
        const float x = raw * a_n + c_n;            // outLin[t,cell]

        // B-ext frag: rows 64..95 of B = [x, 1, 0...] (per cell = lo)
        bf16x8 bx = {};
        {
            const short xb = f2bf(x);
            bx[0] = (hi == 0) ? xb : (short)0;
            bx[1] = (hi == 0) ? (short)0x3F80 : (short)0;   // bf16(1.0)
        }

        // h B-frags: cell = lo, hdims hi*8.. / 32+hi*8..
        const char* hrd = hbuf + (t & 1) * 2304 + lo * 144;
        const bf16x8 bf0 = *(const bf16x8*)(hrd + hi * 16);
        const bf16x8 bf1 = *(const bf16x8*)(hrd + 64 + hi * 16);

        f32x4 acc[4];
        #pragma unroll
        for (int g = 0; g < 4; ++g) {
            acc[g] = __builtin_amdgcn_mfma_f32_16x16x32_bf16(AWf[g][2], bx,  zero4, 0, 0, 0);
            acc[g] = __builtin_amdgcn_mfma_f32_16x16x32_bf16(AWf[g][0], bf0, acc[g], 0, 0, 0);
            acc[g] = __builtin_amdgcn_mfma_f32_16x16x32_bf16(AWf[g][1], bf1, acc[g], 0, 0, 0);
        }

        // softplus(x-1), only wave 0 needs it
        float sp = 0.f;
        if (wv == 0) {
            const float spE = __builtin_amdgcn_exp2f(LOG2E * (x - 1.f));
            sp = LN2 * __builtin_amdgcn_logf(1.f + spE);
        }

        // activations: lane handles (cell=lo, hdim = wv*16 + hi*4 + r)
        float gacc = 0.f;
        float hv[4];
        #pragma unroll
        for (int r = 0; r < 4; ++r) {
            const float ip = acc[0][r];
            const float fp = acc[1][r];
            const float gp = acc[2][r];
            const float op = acc[3][r];

            const float Ei  = __builtin_amdgcn_exp2f(-LOG2E * ip);
            const float Ef  = __builtin_amdgcn_exp2f(-LOG2E * fp);
            const float gpc = __builtin_amdgcn_fmed3f(gp, -15.f, 15.f);
            const float Eg  = __builtin_amdgcn_exp2f(2.f * LOG2E * gpc);
            // c' = sig(f)*c + sig(i)*tanh(g), single rcp:
            const float D1  = 1.f + Ef;
            const float D2  = (Eg + 1.f) * (1.f + Ei);
            const float num = cst[r] * D2 + (Eg - 1.f) * D1;
            const float cp  = num * __builtin_amdgcn_rcpf(D1 * D2);
            cst[r] = cp;
            const float cpc = __builtin_amdgcn_fmed3f(cp, -15.f, 15.f);
            const float Ec  = __builtin_amdgcn_exp2f(2.f * LOG2E * cpc);
            const float Eo  = __builtin_amdgcn_exp2f(-LOG2E * op);
            // h = sig(o)*tanh(c), single rcp:
            const float h   = (Ec - 1.f) *
                __builtin_amdgcn_rcpf((Ec + 1.f) * (1.f + Eo));
            hv[r] = h;
            gacc += h * wgv[r];
        }
        // h-write: hdims wv*16 + hi*4 .. +4 at row lo
        uint2 pk;
        pk.x = cvtpk(hv[0], hv[1]);
        pk.y = cvtpk(hv[2], hv[3]);
        *(uint2*)(hbuf + ((t + 1) & 1) * 2304 + lo * 144 + wv * 32 + hi * 8) = pk;

        // per-wave partial of g_t = sum_h h*wg (this wave's 16 hdims)
        gacc += __shfl_xor(gacc, 16);
        gacc += __shfl_xor(gacc, 32);
        if (hi == 0) gpart[t & 3][wv][lo] = gacc;

        // output: out[t] = g_prev[t] * sp[t]; g_prev = {g_0, 1, g_{t-2}...}
        if (wv == 0) {
            if (t == 0) {
                sp0 = sp;
            } else if (t == 1) {
                if (hi == 0) outP[MCELLS] = sp;
            } else {
                const int s = (t - 2) & 3;
                const float g = gpart[s][0][lo] + gpart[s][1][lo] +
                                gpart[s][2][lo] + gpart[s][3][lo] + bgv;
                if (hi == 0) {
                    outP[t * MCELLS] = g * sp;
                    if (t == 2) outP[0] = g * sp0;   // g_prev[0] = g_0
                }
            }
        }
        __syncthreads();   // h(t+1) visible; gpart ring ordered
    }
}

extern "C" void kernel_launch(void* const* d_in, const int* in_sizes, int n_in,
                              void* d_out, int out_size, void* d_ws, size_t ws_size,
                              hipStream_t stream) {
    const float* input = (const float*)d_in[0];
    const float* w1    = (const float*)d_in[1];
    const float* b1    = (const float*)d_in[2];
    const float* w2    = (const float*)d_in[3];
    const float* b2    = (const float*)d_in[4];
    const float* W_ih  = (const float*)d_in[5];
    const float* W_hh  = (const float*)d_in[6];
    const float* b_ih  = (const float*)d_in[7];
    const float* b_hh  = (const float*)d_in[8];
    const float* wg    = (const float*)d_in[9];
    const float* bg    = (const float*)d_in[10];

    lstm_net_kernel<<<dim3(1024), dim3(256), 0, stream>>>(
        input, w1, b1, w2, b2, W_ih, W_hh, b_ih, b_hh, wg, bg, (float*)d_out);
}

// Round 4
// 761.173 us; speedup vs baseline: 1.2830x; 1.0011x over previous
//
#include <hip/hip_runtime.h>
#include <hip/hip_bf16.h>

#define TT 512
#define MCELLS 16384            // B*N = 256*64
#define LOG2E 1.44269504088896340736f
#define LN2   0.69314718055994530942f

typedef __attribute__((ext_vector_type(8))) short bf16x8;
typedef __attribute__((ext_vector_type(4))) float f32x4;

__device__ __forceinline__ short f2bf(float f) {
    __hip_bfloat16 h = __float2bfloat16(f);
    return __builtin_bit_cast(short, h);
}
// two f32 -> packed bf16 dword (low16 = a, high16 = b), RNE in HW
__device__ __forceinline__ unsigned cvtpk(float a, float b) {
    unsigned r;
    asm("v_cvt_pk_bf16_f32 %0, %1, %2" : "=v"(r) : "v"(a), "v"(b));
    return r;
}

// Persistent LSTM. grid = 1024 blocks x 256 threads (4 waves).
// Each block owns 16 cells (cell = blockIdx*16 + (lane&15)); the four waves
// split the hidden dim: wave w handles hdims [w*16, w*16+16) for all 4 gates
// (jm tile = gate*4 + w). Swapped MFMA D[gate-rows, cell] with A = W_hh rows
// VGPR-resident in frag order, B = h^T from LDS (double-buffered).
// K extended to 96: 3rd MFMA carries x*W_ih + bias (B-ext rows = [x, 1]).
//
// LDS padded to ~38.6 KB so the per-CU residency cap is exactly
// floor(160KB/38.6KB) = 4 blocks/CU -> grid 1024 = 4 x 256 CUs fills the
// WHOLE chip evenly (greedy block dispatch packs CUs to their cap; with an
// 8-block cap only 128 CUs were used).
__global__ __launch_bounds__(256, 4)
void lstm_net_kernel(const float* __restrict__ input,
                     const float* __restrict__ w1,
                     const float* __restrict__ b1,
                     const float* __restrict__ w2,
                     const float* __restrict__ b2,
                     const float* __restrict__ W_ih,
                     const float* __restrict__ W_hh,
                     const float* __restrict__ b_ih,
                     const float* __restrict__ b_hh,
                     const float* __restrict__ wg,
                     const float* __restrict__ bg,
                     float* __restrict__ out)
{
    // h double buffer: 2 x 16 rows(cells) x 144B (64 bf16 + pad; stride 36 dw
    // -> max 2-way bank aliasing on b128 reads, which is free)
    __shared__ __align__(16) char hbuf[2 * 16 * 144];
    __shared__ float gpart[4][4][16];   // ring: slot t&3 written @t, read @t+2
    __shared__ char ldspad[33024];      // residency limiter: 4 blocks/CU

    const int tid  = threadIdx.x;
    const int wv   = tid >> 6;          // 0..3: 16-hdim slice
    const int lane = tid & 63;
    const int lo   = lane & 15;
    const int hi   = lane >> 4;

    if (tid == 0) ldspad[0] = (char)blockIdx.x;   // keep pad allocated

    for (int o = tid; o < (2 * 16 * 144) / 4; o += 256)
        ((unsigned*)hbuf)[o] = 0u;      // h0 = 0 (both buffers)

    // ---- per-cell constants ----
    const int cell = blockIdx.x * 16 + lo;
    const int n    = cell & 63;
    float a_n = 0.f, c_n = 0.f;
    #pragma unroll
    for (int k = 0; k < 10; ++k) {
        a_n += w1[n * 10 + k] * w2[n * 10 + k];   // per-neuron affine collapse
        c_n += b1[n * 10 + k] * w2[n * 10 + k];
    }
    c_n += b2[n];
    const f32x4 wgv = *(const f32x4*)(wg + wv * 16 + hi * 4);
    const float bgv = bg[0];

    // ---- A-fragments resident in VGPRs ----
    // gate g: jm = g*4 + wv ; rows = jm*16 + lo
    bf16x8 AWf[4][3];
    #pragma unroll
    for (int g = 0; g < 4; ++g) {
        const int row = (g * 4 + wv) * 16 + lo;
        #pragma unroll
        for (int kk = 0; kk < 2; ++kk) {
            const float* src = W_hh + row * 64 + kk * 32 + hi * 8;
            bf16x8 v;
            #pragma unroll
            for (int e = 0; e < 8; ++e) v[e] = f2bf(src[e]);
            AWf[g][kk] = v;
        }
        bf16x8 vx = {};                 // K-ext: col64 = W_ih, col65 = bias
        if (hi == 0) {
            vx[0] = f2bf(W_ih[row]);
            vx[1] = f2bf(b_ih[row] + b_hh[row]);
        }
        AWf[g][2] = vx;
    }

    const f32x4 zero4 = {0.f, 0.f, 0.f, 0.f};
    f32x4 cst = zero4;
    float sp0 = 0.f;
    const float* inP  = input + cell;
    float*       outP = out + cell;
    float raw_next = inP[0];

    __syncthreads();

    for (int t = 0; t < TT; ++t) {
        const float raw = raw_next;
        raw_next = inP[((t + 1 < TT) ? (t + 1) : t) * MCELLS];
        const float x = raw * a_n + c_n;            // outLin[t,cell]

        // B-ext frag: rows 64..95 of B = [x, 1, 0...] (per cell = lo)
        bf16x8 bx = {};
        {
            const short xb = f2bf(x);
            bx[0] = (hi == 0) ? xb : (short)0;
            bx[1] = (hi == 0) ? (short)0x3F80 : (short)0;   // bf16(1.0)
        }

        // h B-frags: cell = lo, hdims hi*8.. / 32+hi*8..
        const char* hrd = hbuf + (t & 1) * 2304 + lo * 144;
        const bf16x8 bf0 = *(const bf16x8*)(hrd + hi * 16);
        const bf16x8 bf1 = *(const bf16x8*)(hrd + 64 + hi * 16);

        f32x4 acc[4];
        #pragma unroll
        for (int g = 0; g < 4; ++g) {
            acc[g] = __builtin_amdgcn_mfma_f32_16x16x32_bf16(AWf[g][2], bx,  zero4, 0, 0, 0);
            acc[g] = __builtin_amdgcn_mfma_f32_16x16x32_bf16(AWf[g][0], bf0, acc[g], 0, 0, 0);
            acc[g] = __builtin_amdgcn_mfma_f32_16x16x32_bf16(AWf[g][1], bf1, acc[g], 0, 0, 0);
        }

        // softplus(x-1), only wave 0 needs it
        float sp = 0.f;
        if (wv == 0) {
            const float spE = __builtin_amdgcn_exp2f(LOG2E * (x - 1.f));
            sp = LN2 * __builtin_amdgcn_logf(1.f + spE);
        }

        // activations: lane handles (cell=lo, hdim = wv*16 + hi*4 + r)
        float gacc = 0.f;
        float hv[4];
        #pragma unroll
        for (int r = 0; r < 4; ++r) {
            const float ip = acc[0][r];
            const float fp = acc[1][r];
            const float gp = acc[2][r];
            const float op = acc[3][r];

            const float Ei  = __builtin_amdgcn_exp2f(-LOG2E * ip);
            const float Ef  = __builtin_amdgcn_exp2f(-LOG2E * fp);
            const float gpc = __builtin_amdgcn_fmed3f(gp, -15.f, 15.f);
            const float Eg  = __builtin_amdgcn_exp2f(2.f * LOG2E * gpc);
            // c' = sig(f)*c + sig(i)*tanh(g), single rcp:
            const float D1  = 1.f + Ef;
            const float D2  = (Eg + 1.f) * (1.f + Ei);
            const float num = cst[r] * D2 + (Eg - 1.f) * D1;
            const float cp  = num * __builtin_amdgcn_rcpf(D1 * D2);
            cst[r] = cp;
            const float cpc = __builtin_amdgcn_fmed3f(cp, -15.f, 15.f);
            const float Ec  = __builtin_amdgcn_exp2f(2.f * LOG2E * cpc);
            const float Eo  = __builtin_amdgcn_exp2f(-LOG2E * op);
            // h = sig(o)*tanh(c), single rcp:
            const float h   = (Ec - 1.f) *
                __builtin_amdgcn_rcpf((Ec + 1.f) * (1.f + Eo));
            hv[r] = h;
            gacc += h * wgv[r];
        }
        // h-write: hdims wv*16 + hi*4 .. +4 at row lo
        uint2 pk;
        pk.x = cvtpk(hv[0], hv[1]);
        pk.y = cvtpk(hv[2], hv[3]);
        *(uint2*)(hbuf + ((t + 1) & 1) * 2304 + lo * 144 + wv * 32 + hi * 8) = pk;

        // per-wave partial of g_t = sum_h h*wg (this wave's 16 hdims)
        gacc += __shfl_xor(gacc, 16);
        gacc += __shfl_xor(gacc, 32);
        if (hi == 0) gpart[t & 3][wv][lo] = gacc;

        // output: out[t] = g_prev[t] * sp[t]; g_prev = {g_0, 1, g_{t-2}...}
        if (wv == 0) {
            if (t == 0) {
                sp0 = sp;
            } else if (t == 1) {
                if (hi == 0) outP[MCELLS] = sp;
            } else {
                const int s = (t - 2) & 3;
                const float g = gpart[s][0][lo] + gpart[s][1][lo] +
                                gpart[s][2][lo] + gpart[s][3][lo] + bgv;
                if (hi == 0) {
                    outP[t * MCELLS] = g * sp;
                    if (t == 2) outP[0] = g * sp0;   // g_prev[0] = g_0
                }
            }
        }
        __syncthreads();   // h(t+1) visible; gpart ring ordered
    }
}

extern "C" void kernel_launch(void* const* d_in, const int* in_sizes, int n_in,
                              void* d_out, int out_size, void* d_ws, size_t ws_size,
                              hipStream_t stream) {
    const float* input = (const float*)d_in[0];
    const float* w1    = (const float*)d_in[1];
    const float* b1    = (const float*)d_in[2];
    const float* w2    = (const float*)d_in[3];
    const float* b2    = (const float*)d_in[4];
    const float* W_ih  = (const float*)d_in[5];
    const float* W_hh  = (const float*)d_in[6];
    const float* b_ih  = (const float*)d_in[7];
    const float* b_hh  = (const float*)d_in[8];
    const float* wg    = (const float*)d_in[9];
    const float* bg    = (const float*)d_in[10];

    lstm_net_kernel<<<dim3(1024), dim3(256), 0, stream>>>(
        input, w1, b1, w2, b2, W_ih, W_hh, b_ih, b_hh, wg, bg, (float*)d_out);
}

// Round 5
// 760.632 us; speedup vs baseline: 1.2839x; 1.0007x over previous
//
#include <hip/hip_runtime.h>
#include <hip/hip_bf16.h>

#define TT 512
#define MCELLS 16384            // B*N = 256*64
#define LOG2E 1.44269504088896340736f
#define LN2   0.69314718055994530942f

typedef __attribute__((ext_vector_type(8))) short bf16x8;
typedef __attribute__((ext_vector_type(4))) float f32x4;

__device__ __forceinline__ short f2bf(float f) {
    __hip_bfloat16 h = __float2bfloat16(f);
    return __builtin_bit_cast(short, h);
}
// two f32 -> packed bf16 dword (low16 = a, high16 = b), RNE in HW
__device__ __forceinline__ unsigned cvtpk(float a, float b) {
    unsigned r;
    asm("v_cvt_pk_bf16_f32 %0, %1, %2" : "=v"(r) : "v"(a), "v"(b));
    return r;
}

// Persistent LSTM. grid = 1024 blocks x 256 threads (4 waves).
// Each block owns 16 cells (cell = blockIdx*16 + (lane&15)); the four waves
// split the hidden dim: wave w handles hdims [w*16, w*16+16) for all 4 gates
// (jm tile = gate*4 + w). Swapped MFMA D[gate-rows, cell] with A = W_hh rows
// VGPR-resident in frag order, B = h^T from LDS (double-buffered).
// K extended to 96: 3rd MFMA carries x*W_ih + bias (B-ext rows = [x, 1]).
//
// Residency limiter: 34 KB of DYNAMIC shared memory (launch-config, cannot be
// DCE'd -- the static-array attempt in R3 was eliminated by the compiler).
// Total LDS ~39.6 KB -> exactly 4 blocks/CU -> 1024 blocks spread over all
// 256 CUs instead of greedy-packing 8/CU onto only 128 CUs.
__global__ __launch_bounds__(256, 4)
void lstm_net_kernel(const float* __restrict__ input,
                     const float* __restrict__ w1,
                     const float* __restrict__ b1,
                     const float* __restrict__ w2,
                     const float* __restrict__ b2,
                     const float* __restrict__ W_ih,
                     const float* __restrict__ W_hh,
                     const float* __restrict__ b_ih,
                     const float* __restrict__ b_hh,
                     const float* __restrict__ wg,
                     const float* __restrict__ bg,
                     float* __restrict__ out)
{
    extern __shared__ char dynpad[];    // residency limiter (34 KB at launch)
    // h double buffer: 2 x 16 rows(cells) x 144B (64 bf16 + pad; stride 36 dw
    // -> max 2-way bank aliasing on b128 reads, which is free)
    __shared__ __align__(16) char hbuf[2 * 16 * 144];
    __shared__ float gpart[4][4][16];   // ring: slot t&3 written @t, read @t+2

    const int tid  = threadIdx.x;
    const int wv   = tid >> 6;          // 0..3: 16-hdim slice
    const int lane = tid & 63;
    const int lo   = lane & 15;
    const int hi   = lane >> 4;

    for (int o = tid; o < (2 * 16 * 144) / 4; o += 256)
        ((unsigned*)hbuf)[o] = 0u;      // h0 = 0 (both buffers)

    // ---- per-cell constants ----
    const int cell = blockIdx.x * 16 + lo;
    const int n    = cell & 63;
    float a_n = 0.f, c_n = 0.f;
    #pragma unroll
    for (int k = 0; k < 10; ++k) {
        a_n += w1[n * 10 + k] * w2[n * 10 + k];   // per-neuron affine collapse
        c_n += b1[n * 10 + k] * w2[n * 10 + k];
    }
    c_n += b2[n];
    const f32x4 wgv = *(const f32x4*)(wg + wv * 16 + hi * 4);
    const float bgv = bg[0];

    // ---- A-fragments resident in VGPRs ----
    // gate g: jm = g*4 + wv ; rows = jm*16 + lo
    bf16x8 AWf[4][3];
    #pragma unroll
    for (int g = 0; g < 4; ++g) {
        const int row = (g * 4 + wv) * 16 + lo;
        #pragma unroll
        for (int kk = 0; kk < 2; ++kk) {
            const float* src = W_hh + row * 64 + kk * 32 + hi * 8;
            bf16x8 v;
            #pragma unroll
            for (int e = 0; e < 8; ++e) v[e] = f2bf(src[e]);
            AWf[g][kk] = v;
        }
        bf16x8 vx = {};                 // K-ext: col64 = W_ih, col65 = bias
        if (hi == 0) {
            vx[0] = f2bf(W_ih[row]);
            vx[1] = f2bf(b_ih[row] + b_hh[row]);
        }
        AWf[g][2] = vx;
    }

    const f32x4 zero4 = {0.f, 0.f, 0.f, 0.f};
    f32x4 cst = zero4;
    float sp0 = 0.f;
    const float* inP  = input + cell;
    float*       outP = out + cell;
    float raw_next = inP[0];

    __syncthreads();

    for (int t = 0; t < TT; ++t) {
        const float raw = raw_next;
        raw_next = inP[((t + 1 < TT) ? (t + 1) : t) * MCELLS];
        const float x = raw * a_n + c_n;            // outLin[t,cell]

        // B-ext frag: rows 64..95 of B = [x, 1, 0...] (per cell = lo)
        bf16x8 bx = {};
        {
            const short xb = f2bf(x);
            bx[0] = (hi == 0) ? xb : (short)0;
            bx[1] = (hi == 0) ? (short)0x3F80 : (short)0;   // bf16(1.0)
        }

        // h B-frags: cell = lo, hdims hi*8.. / 32+hi*8..
        const char* hrd = hbuf + (t & 1) * 2304 + lo * 144;
        const bf16x8 bf0 = *(const bf16x8*)(hrd + hi * 16);
        const bf16x8 bf1 = *(const bf16x8*)(hrd + 64 + hi * 16);

        f32x4 acc[4];
        #pragma unroll
        for (int g = 0; g < 4; ++g) {
            acc[g] = __builtin_amdgcn_mfma_f32_16x16x32_bf16(AWf[g][2], bx,  zero4, 0, 0, 0);
            acc[g] = __builtin_amdgcn_mfma_f32_16x16x32_bf16(AWf[g][0], bf0, acc[g], 0, 0, 0);
            acc[g] = __builtin_amdgcn_mfma_f32_16x16x32_bf16(AWf[g][1], bf1, acc[g], 0, 0, 0);
        }

        // softplus(x-1), only wave 0 needs it
        float sp = 0.f;
        if (wv == 0) {
            const float spE = __builtin_amdgcn_exp2f(LOG2E * (x - 1.f));
            sp = LN2 * __builtin_amdgcn_logf(1.f + spE);
        }

        // activations: lane handles (cell=lo, hdim = wv*16 + hi*4 + r)
        float gacc = 0.f;
        float hv[4];
        #pragma unroll
        for (int r = 0; r < 4; ++r) {
            const float ip = acc[0][r];
            const float fp = acc[1][r];
            const float gp = acc[2][r];
            const float op = acc[3][r];

            const float Ei  = __builtin_amdgcn_exp2f(-LOG2E * ip);
            const float Ef  = __builtin_amdgcn_exp2f(-LOG2E * fp);
            const float gpc = __builtin_amdgcn_fmed3f(gp, -15.f, 15.f);
            const float Eg  = __builtin_amdgcn_exp2f(2.f * LOG2E * gpc);
            // c' = sig(f)*c + sig(i)*tanh(g), single rcp:
            const float D1  = 1.f + Ef;
            const float D2  = (Eg + 1.f) * (1.f + Ei);
            const float num = cst[r] * D2 + (Eg - 1.f) * D1;
            const float cp  = num * __builtin_amdgcn_rcpf(D1 * D2);
            cst[r] = cp;
            const float cpc = __builtin_amdgcn_fmed3f(cp, -15.f, 15.f);
            const float Ec  = __builtin_amdgcn_exp2f(2.f * LOG2E * cpc);
            const float Eo  = __builtin_amdgcn_exp2f(-LOG2E * op);
            // h = sig(o)*tanh(c), single rcp:
            const float h   = (Ec - 1.f) *
                __builtin_amdgcn_rcpf((Ec + 1.f) * (1.f + Eo));
            hv[r] = h;
            gacc += h * wgv[r];
        }
        // h-write: hdims wv*16 + hi*4 .. +4 at row lo
        uint2 pk;
        pk.x = cvtpk(hv[0], hv[1]);
        pk.y = cvtpk(hv[2], hv[3]);
        *(uint2*)(hbuf + ((t + 1) & 1) * 2304 + lo * 144 + wv * 32 + hi * 8) = pk;

        // per-wave partial of g_t = sum_h h*wg (this wave's 16 hdims)
        gacc += __shfl_xor(gacc, 16);
        gacc += __shfl_xor(gacc, 32);
        if (hi == 0) gpart[t & 3][wv][lo] = gacc;

        // output: out[t] = g_prev[t] * sp[t]; g_prev = {g_0, 1, g_{t-2}...}
        if (wv == 0) {
            if (t == 0) {
                sp0 = sp;
            } else if (t == 1) {
                if (hi == 0) outP[MCELLS] = sp;
            } else {
                const int s = (t - 2) & 3;
                const float g = gpart[s][0][lo] + gpart[s][1][lo] +
                                gpart[s][2][lo] + gpart[s][3][lo] + bgv;
                if (hi == 0) {
                    outP[t * MCELLS] = g * sp;
                    if (t == 2) outP[0] = g * sp0;   // g_prev[0] = g_0
                }
            }
        }
        __syncthreads();   // h(t+1) visible; gpart ring ordered
    }
}

extern "C" void kernel_launch(void* const* d_in, const int* in_sizes, int n_in,
                              void* d_out, int out_size, void* d_ws, size_t ws_size,
                              hipStream_t stream) {
    const float* input = (const float*)d_in[0];
    const float* w1    = (const float*)d_in[1];
    const float* b1    = (const float*)d_in[2];
    const float* w2    = (const float*)d_in[3];
    const float* b2    = (const float*)d_in[4];
    const float* W_ih  = (const float*)d_in[5];
    const float* W_hh  = (const float*)d_in[6];
    const float* b_ih  = (const float*)d_in[7];
    const float* b_hh  = (const float*)d_in[8];
    const float* wg    = (const float*)d_in[9];
    const float* bg    = (const float*)d_in[10];

    // 34 KB dynamic LDS: residency limiter (4 blocks/CU) -- see kernel comment.
    lstm_net_kernel<<<dim3(1024), dim3(256), 34816, stream>>>(
        input, w1, b1, w2, b2, W_ih, W_hh, b_ih, b_hh, wg, bg, (float*)d_out);
}